// Round 16
// baseline (290.321 us; speedup 1.0000x reference)
//
#include <hip/hip_runtime.h>

#define VOCAB   50000
#define LDIM    8921
#define DDIM    300
#define DPAD    320
#define KSZ     10
#define BATCH   8
#define TSEQ    2048
#define PADL    9
#define TPRIME  2057
#define TPADDED 2066
#define LPAD    8928

// ---- attn tiling
#define TSTG    32                 // t rows per LDS tile
#define NTT     65                 // ceil(TPRIME/TSTG)
#define TALLOC  (NTT * TSTG)       // 2080 h rows per batch (tail rows zeroed by conv)
#define LBLK    70                 // ceil(LDIM/128) l-blocks

typedef short s8v __attribute__((ext_vector_type(8)));   // 8 x bf16 bits
typedef float f4v __attribute__((ext_vector_type(4)));

typedef const __attribute__((address_space(1))) unsigned int* gas_ptr;
typedef __attribute__((address_space(3))) unsigned int* las_ptr;

__device__ inline unsigned short f2bf(float f) {
  union { float f; unsigned u; } v; v.f = f;
  unsigned r = v.u + 0x7FFF + ((v.u >> 16) & 1);
  return (unsigned short)(r >> 16);
}

// ---- K1: conv weight transform ONLY (r16: Ub eliminated — attn converts U
// in-kernel). One block per o: threads read w[o][i][0..9] (10 CONTIGUOUS
// floats; consecutive threads +40B -> fully coalesced wave reads, replacing
// the old 40B-strided pattern) and scatter 10 wave-coalesced bf16 stores.
// Grid 12128 -> 320 blocks.
__global__ __launch_bounds__(256) void prep_kernel(
    const float* __restrict__ w, unsigned short* __restrict__ wT) {
  int o = blockIdx.x;                        // 0..319 (o >= DDIM -> zero rows)
  for (int i = threadIdx.x; i < DPAD; i += 256) {
    float vv[KSZ];
    if (o < DDIM && i < DDIM) {
      const float* src = w + ((size_t)o * DDIM + i) * KSZ;
#pragma unroll
      for (int k = 0; k < KSZ; ++k) vv[k] = src[k];
    } else {
#pragma unroll
      for (int k = 0; k < KSZ; ++k) vv[k] = 0.0f;
    }
#pragma unroll
    for (int k = 0; k < KSZ; ++k)
      wT[((size_t)k * DPAD + o) * DPAD + i] = f2bf(vv[k]);
  }
}

// ---- K2: conv via MFMA, fused embedding gather — EXACT r11 form (proven 82us
// slice; r12 8-wave/r14 k-split/r15 B-pipeline all null or worse). Grid 208 =
// 8 x 26, <=1 block/CU, acc[5][5], dist-2 Aping/Apong wT pipeline, bare (256).
#define CTN 80
#define CROWS 89          // CTN + KSZ - 1
#define CSTRIDE 328       // 656B/row -> benign 2-way conflicts
__global__ __launch_bounds__(256) void conv_mfma_kernel(
    const int* __restrict__ ids, const float* __restrict__ embed_w,
    const unsigned short* __restrict__ wT,
    const float* __restrict__ bias, unsigned short* __restrict__ h) {
  __shared__ unsigned short xls[CROWS * CSTRIDE];   // 58384 B
  int b = blockIdx.x & 7, tb = blockIdx.x >> 3;     // grid 208 = 8 x 26
  int t0 = tb * CTN;
  int tid = threadIdx.x;
  {
    const int* idsb = ids + b * TSEQ;
    for (int idx = tid; idx < CROWS * 40; idx += 256) {
      int rr = idx / 40, c8 = idx % 40;
      int tau = t0 + rr;
      bool inr = (tau >= PADL) && (tau < PADL + TSEQ);
      unsigned short pk[8];
      if (inr) {
        int row = idsb[tau - PADL];
        const float* src = embed_w + (size_t)row * DDIM + c8 * 8;
        float4 lo = (c8 * 8 + 3 < DDIM) ? *(const float4*)&src[0] : make_float4(0, 0, 0, 0);
        float4 hi = (c8 * 8 + 7 < DDIM) ? *(const float4*)&src[4] : make_float4(0, 0, 0, 0);
        pk[0] = f2bf(lo.x); pk[1] = f2bf(lo.y); pk[2] = f2bf(lo.z); pk[3] = f2bf(lo.w);
        pk[4] = f2bf(hi.x); pk[5] = f2bf(hi.y); pk[6] = f2bf(hi.z); pk[7] = f2bf(hi.w);
      } else {
#pragma unroll
        for (int e = 0; e < 8; ++e) pk[e] = 0;
      }
      *(int4*)&xls[rr * CSTRIDE + c8 * 8] = *(const int4*)pk;
    }
  }
  __syncthreads();
  int w = tid >> 6, lane = tid & 63;
  int l15 = lane & 15, quad = lane >> 4;
  int ob = w * 80;                                  // o-quadrant per wave
  f4v acc[5][5];
#pragma unroll
  for (int mf = 0; mf < 5; ++mf) {
    float bv[4];
#pragma unroll
    for (int rr = 0; rr < 4; ++rr) {
      int o = ob + mf * 16 + quad * 4 + rr;
      bv[rr] = (o < DDIM) ? bias[o] : 0.0f;
    }
#pragma unroll
    for (int nf = 0; nf < 5; ++nf) {
      acc[mf][nf][0] = bv[0]; acc[mf][nf][1] = bv[1];
      acc[mf][nf][2] = bv[2]; acc[mf][nf][3] = bv[3];
    }
  }
  // A-frag (kc,it,mf) at wl[kc*DPAD*DPAD + mf*16*DPAD + it*32]
  const unsigned short* wl = wT + (size_t)(ob + l15) * DPAD + quad * 8;
  s8v Aping[5], Apong[5];
#pragma unroll
  for (int mf = 0; mf < 5; ++mf) Aping[mf] = *(const s8v*)&wl[mf * 16 * DPAD];        // (0,0)
#pragma unroll
  for (int mf = 0; mf < 5; ++mf) Apong[mf] = *(const s8v*)&wl[mf * 16 * DPAD + 32];   // (0,1)
  for (int ii = 0; ii < 100; ii += 2) {
    // ---- even sub-iter: frags (ii) in Aping
    {
      int kc = ii / 10, it = ii % 10;
      s8v Bv[5];
#pragma unroll
      for (int nf = 0; nf < 5; ++nf)
        Bv[nf] = *(const s8v*)&xls[(nf * 16 + l15 + kc) * CSTRIDE + it * 32 + quad * 8];
#pragma unroll
      for (int mf = 0; mf < 5; ++mf)
#pragma unroll
        for (int nf = 0; nf < 5; ++nf)
          acc[mf][nf] = __builtin_amdgcn_mfma_f32_16x16x32_bf16(Aping[mf], Bv[nf], acc[mf][nf], 0, 0, 0);
      int p = ii + 2;
      if (p < 100) {
        int kp = p / 10, itp = p % 10;
        const unsigned short* wp = wl + (size_t)kp * (DPAD * DPAD) + itp * 32;
#pragma unroll
        for (int mf = 0; mf < 5; ++mf) Aping[mf] = *(const s8v*)&wp[mf * 16 * DPAD];
      }
    }
    // ---- odd sub-iter: frags (ii+1) in Apong
    {
      int kc = (ii + 1) / 10, it = (ii + 1) % 10;
      s8v Bv[5];
#pragma unroll
      for (int nf = 0; nf < 5; ++nf)
        Bv[nf] = *(const s8v*)&xls[(nf * 16 + l15 + kc) * CSTRIDE + it * 32 + quad * 8];
#pragma unroll
      for (int mf = 0; mf < 5; ++mf)
#pragma unroll
        for (int nf = 0; nf < 5; ++nf)
          acc[mf][nf] = __builtin_amdgcn_mfma_f32_16x16x32_bf16(Apong[mf], Bv[nf], acc[mf][nf], 0, 0, 0);
      int p = ii + 3;
      if (p < 100) {
        int kp = p / 10, itp = p % 10;
        const unsigned short* wp = wl + (size_t)kp * (DPAD * DPAD) + itp * 32;
#pragma unroll
        for (int mf = 0; mf < 5; ++mf) Apong[mf] = *(const s8v*)&wp[mf * 16 * DPAD];
      }
    }
  }
#pragma unroll
  for (int mf = 0; mf < 5; ++mf) {
    int obase = ob + mf * 16 + quad * 4;
#pragma unroll
    for (int nf = 0; nf < 5; ++nf) {
      int t = t0 + nf * 16 + l15;            // always < TALLOC (26x80 = 2080 exact)
      bool live = t < TPRIME;
      unsigned short pk[4];
#pragma unroll
      for (int rr = 0; rr < 4; ++rr)
        pk[rr] = live ? f2bf(fmaxf(acc[mf][nf][rr], 0.0f)) : (unsigned short)0;
      *(uint2*)&h[((size_t)b * TALLOC + t) * DPAD + obase] = *(uint2*)pk;
    }
  }
}

// ---- K3: scores (U . h) via MFMA + fused softmax-weighted mean.
// FROZEN r5/r6/r11 structure (119us local optimum). r16 change: A-frags
// converted DIRECTLY from f32 U in-kernel (guarded float4 loads + f2bf,
// once per block) — kills the Ub workspace and the 8928-block half of prep.
// 4 waves, depth-1 DMA double-buffer, vmcnt(0)+barrier per tile, 560 blocks
// co-resident at (256,3). Unmasked softmax + (-23) phantom correction.
__global__ __launch_bounds__(256, 3) void attn_mfma_kernel(
    const unsigned short* __restrict__ h, const float* __restrict__ U,
    const float* __restrict__ fcb, float* __restrict__ out) {
  __shared__ unsigned short hls[2 * TSTG * DPAD];   // 2 x 10240 elems = 40960B
  int b = blockIdx.x & 7, lb = blockIdx.x >> 3;
  int tid = threadIdx.x;
  int w = tid >> 6, lane = tid & 63;
  int l15 = lane & 15, quad = lane >> 4;
  const unsigned short* hb = h + (size_t)b * TALLOC * DPAD;

  // A fragments: wave covers 32 l-rows; convert f32 U -> bf16 in-register.
  // Guards reproduce the old Ub zero-padding exactly (l >= LDIM or d >= DDIM
  // -> 0); float4 chunks are 16B-aligned (row stride 1200B, d multiple of 4).
  s8v A[2][10];
  {
    int lr0 = lb * 128 + w * 32 + l15;
#pragma unroll
    for (int mf = 0; mf < 2; ++mf) {
      int lr = lr0 + mf * 16;
      bool lok = lr < LDIM;
      const float* up = U + (size_t)lr * DDIM;
#pragma unroll
      for (int kc = 0; kc < 10; ++kc) {
        unsigned short pk[8];
#pragma unroll
        for (int half = 0; half < 2; ++half) {
          int dd = kc * 32 + quad * 8 + half * 4;
          float4 v = (lok && dd + 3 < DDIM) ? *(const float4*)&up[dd]
                                            : make_float4(0.0f, 0.0f, 0.0f, 0.0f);
          pk[half * 4 + 0] = f2bf(v.x); pk[half * 4 + 1] = f2bf(v.y);
          pk[half * 4 + 2] = f2bf(v.z); pk[half * 4 + 3] = f2bf(v.w);
        }
        A[mf][kc] = *(const s8v*)pk;
      }
    }
  }

  // DMA staging map: wave w fills LDS elems [w*2560, w*2560+2560) in 5 x 1KB.
  // lane's LDS chunk g = w*320 + j*64 + lane -> row r = g/40, chunk c = g%40;
  // global source chunk = c ^ (r&7)  (involution, same XOR on read side)
  int srcoff[5];
#pragma unroll
  for (int j = 0; j < 5; ++j) {
    int g = w * 320 + j * 64 + lane;
    int r = g / 40, c = g % 40;
    srcoff[j] = r * DPAD + ((c ^ (r & 7)) * 8);
  }

  // prologue: DMA tile 0 -> buf0
#pragma unroll
  for (int j = 0; j < 5; ++j)
    __builtin_amdgcn_global_load_lds((gas_ptr)(const void*)(hb + srcoff[j]),
                                     (las_ptr)(void*)&hls[w * 2560 + j * 512],
                                     16, 0, 0);
  asm volatile("s_waitcnt vmcnt(0)" ::: "memory");
  __builtin_amdgcn_s_barrier();

  float se[2][4], sw[2][4];
#pragma unroll
  for (int mf = 0; mf < 2; ++mf)
#pragma unroll
    for (int r = 0; r < 4; ++r) { se[mf][r] = 0.0f; sw[mf][r] = 0.0f; }

  int xr8 = (l15 & 7) * 8;            // read-side XOR (elem units)
  int rowb0 = l15 * DPAD;             // nf=0 row base
  int rowb1 = (16 + l15) * DPAD;      // nf=1 row base
  int bufsel = 0;
  const f4v vzero = {0.0f, 0.0f, 0.0f, 0.0f};
  for (int t = 0; t < NTT; ++t) {
    // issue DMA for tile t+1 into the other buffer (latency hidden by compute)
    if (t + 1 < NTT) {
      const unsigned short* src = hb + (size_t)(t + 1) * TSTG * DPAD;
      int dstb = (bufsel ^ 1) * 10240 + w * 2560;
#pragma unroll
      for (int j = 0; j < 5; ++j)
        __builtin_amdgcn_global_load_lds((gas_ptr)(const void*)(src + srcoff[j]),
                                         (las_ptr)(void*)&hls[dstb + j * 512],
                                         16, 0, 0);
    }
    const unsigned short* bufc = &hls[bufsel * 10240];
    f4v a00, a01, a10, a11;
    __builtin_amdgcn_s_setprio(1);
    {
      int ko = (quad * 8) ^ xr8;
      s8v Bv0 = *(const s8v*)&bufc[rowb0 + ko];
      s8v Bv1 = *(const s8v*)&bufc[rowb1 + ko];
      a00 = __builtin_amdgcn_mfma_f32_16x16x32_bf16(A[0][0], Bv0, vzero, 0, 0, 0);
      a01 = __builtin_amdgcn_mfma_f32_16x16x32_bf16(A[0][0], Bv1, vzero, 0, 0, 0);
      a10 = __builtin_amdgcn_mfma_f32_16x16x32_bf16(A[1][0], Bv0, vzero, 0, 0, 0);
      a11 = __builtin_amdgcn_mfma_f32_16x16x32_bf16(A[1][0], Bv1, vzero, 0, 0, 0);
    }
#pragma unroll
    for (int kc = 1; kc < 10; ++kc) {
      int ko = (kc * 32 + quad * 8) ^ xr8;
      s8v Bv0 = *(const s8v*)&bufc[rowb0 + ko];
      s8v Bv1 = *(const s8v*)&bufc[rowb1 + ko];
      a00 = __builtin_amdgcn_mfma_f32_16x16x32_bf16(A[0][kc], Bv0, a00, 0, 0, 0);
      a01 = __builtin_amdgcn_mfma_f32_16x16x32_bf16(A[0][kc], Bv1, a01, 0, 0, 0);
      a10 = __builtin_amdgcn_mfma_f32_16x16x32_bf16(A[1][kc], Bv0, a10, 0, 0, 0);
      a11 = __builtin_amdgcn_mfma_f32_16x16x32_bf16(A[1][kc], Bv1, a11, 0, 0, 0);
    }
    __builtin_amdgcn_s_setprio(0);
    // unmasked fused softmax accumulation (tail h rows are exact zeros ->
    // s=0 -> e=1; corrected after the reduction)
#pragma unroll
    for (int r = 0; r < 4; ++r) {
      float s0 = a00[r], s1 = a01[r];
      float e0 = __expf(s0), e1 = __expf(s1);
      se[0][r] += e0 + e1;
      sw[0][r] = fmaf(e0, s0, sw[0][r]);
      sw[0][r] = fmaf(e1, s1, sw[0][r]);
      float s2 = a10[r], s3 = a11[r];
      float e2 = __expf(s2), e3 = __expf(s3);
      se[1][r] += e2 + e3;
      sw[1][r] = fmaf(e2, s2, sw[1][r]);
      sw[1][r] = fmaf(e3, s3, sw[1][r]);
    }
    // drain this iter's DMA (issued a full tile of compute ago), sync, swap
    asm volatile("s_waitcnt vmcnt(0)" ::: "memory");
    __builtin_amdgcn_s_barrier();
    bufsel ^= 1;
  }

  // reduce over the 16 t-columns (l15 lanes); subtract the 23 phantom columns
  // (TALLOC - TPRIME, each contributing exactly exp(0)=1) from the denominator.
#pragma unroll
  for (int mf = 0; mf < 2; ++mf)
#pragma unroll
    for (int r = 0; r < 4; ++r) {
      float a = se[mf][r], c = sw[mf][r];
#pragma unroll
      for (int off = 1; off < 16; off <<= 1) {
        a += __shfl_xor(a, off, 64);
        c += __shfl_xor(c, off, 64);
      }
      if (l15 == 0) {
        int l = lb * 128 + w * 32 + mf * 16 + quad * 4 + r;
        if (l < LDIM) out[(size_t)b * LDIM + l] = c / (a - 23.0f) + fcb[l];
      }
    }
}

extern "C" void kernel_launch(void* const* d_in, const int* in_sizes, int n_in,
                              void* d_out, int out_size, void* d_ws, size_t ws_size,
                              hipStream_t stream) {
  const int*   ids     = (const int*)d_in[0];
  const float* embed_w = (const float*)d_in[1];
  const float* conv_w  = (const float*)d_in[2];
  const float* conv_b  = (const float*)d_in[3];
  const float* U       = (const float*)d_in[4];
  const float* fc_bias = (const float*)d_in[5];
  float* out = (float*)d_out;

  unsigned char* p = (unsigned char*)d_ws;
  unsigned short* hb = (unsigned short*)p;                 p += (size_t)BATCH * TALLOC * DPAD * 2;
  unsigned short* wT = (unsigned short*)p;

  hipLaunchKernelGGL(prep_kernel, dim3(DPAD), dim3(256), 0, stream,
                     conv_w, wT);
  hipLaunchKernelGGL(conv_mfma_kernel, dim3(BATCH * 26), dim3(256), 0, stream,
                     ids, embed_w, wT, conv_b, hb);
  hipLaunchKernelGGL(attn_mfma_kernel, dim3(BATCH * LBLK), dim3(256), 0, stream,
                     hb, U, fc_bias, out);
}

// Round 17
// 288.579 us; speedup vs baseline: 1.0060x; 1.0060x over previous
//
#include <hip/hip_runtime.h>

#define VOCAB   50000
#define LDIM    8921
#define DDIM    300
#define DPAD    320
#define KSZ     10
#define BATCH   8
#define TSEQ    2048
#define PADL    9
#define TPRIME  2057
#define TPADDED 2066
#define LPAD    8928

// ---- attn tiling
#define TSTG    32                 // t rows per LDS tile
#define NTT     65                 // ceil(TPRIME/TSTG)
#define TALLOC  (NTT * TSTG)       // 2080 h rows per batch (tail rows zeroed by conv)
#define LBLK    70                 // ceil(LDIM/128) l-blocks

typedef short s8v __attribute__((ext_vector_type(8)));   // 8 x bf16 bits
typedef float f4v __attribute__((ext_vector_type(4)));

typedef const __attribute__((address_space(1))) unsigned int* gas_ptr;
typedef __attribute__((address_space(3))) unsigned int* las_ptr;

__device__ inline unsigned short f2bf(float f) {
  union { float f; unsigned u; } v; v.f = f;
  unsigned r = v.u + 0x7FFF + ((v.u >> 16) & 1);
  return (unsigned short)(r >> 16);
}

// ---- K1: fused prep. Blocks 0..319: wT transform with COALESCED reads
// (r16's pattern: one block per o, each thread reads w[o][i][0..9] = 10
// contiguous floats; consecutive threads +40B -> fully coalesced; 10
// wave-coalesced bf16 scatter stores). Blocks 320..9247: Ub transform
// (r11 pattern — KEPT: r16 showed attn reading f32 U directly doubles HBM
// traffic, FETCH 27.7->52.7MB, +9us; the shared bf16 Ub is the right form).
__global__ __launch_bounds__(256) void prep_kernel(
    const float* __restrict__ w, const float* __restrict__ U,
    unsigned short* __restrict__ wT, unsigned short* __restrict__ Ub) {
  int bid = blockIdx.x;
  if (bid < DPAD) {
    int o = bid;                              // o >= DDIM -> zero rows
    for (int i = threadIdx.x; i < DPAD; i += 256) {
      float vv[KSZ];
      if (o < DDIM && i < DDIM) {
        const float* src = w + ((size_t)o * DDIM + i) * KSZ;
#pragma unroll
        for (int k = 0; k < KSZ; ++k) vv[k] = src[k];
      } else {
#pragma unroll
        for (int k = 0; k < KSZ; ++k) vv[k] = 0.0f;
      }
#pragma unroll
      for (int k = 0; k < KSZ; ++k)
        wT[((size_t)k * DPAD + o) * DPAD + i] = f2bf(vv[k]);
    }
  } else {
    int l = bid - DPAD;
    for (int d = threadIdx.x; d < DPAD; d += 256) {
      float v = (l < LDIM && d < DDIM) ? U[(size_t)l * DDIM + d] : 0.0f;
      Ub[(size_t)l * DPAD + d] = f2bf(v);
    }
  }
}

// ---- K2: conv via MFMA, fused embedding gather — EXACT r11 form (proven;
// r12 8-wave demotion, r14 k-split null, r15 B-pipeline null). Grid 208 =
// 8 x 26, <=1 block/CU, acc[5][5], dist-2 Aping/Apong wT pipeline, bare (256).
#define CTN 80
#define CROWS 89          // CTN + KSZ - 1
#define CSTRIDE 328       // 656B/row -> benign 2-way conflicts
__global__ __launch_bounds__(256) void conv_mfma_kernel(
    const int* __restrict__ ids, const float* __restrict__ embed_w,
    const unsigned short* __restrict__ wT,
    const float* __restrict__ bias, unsigned short* __restrict__ h) {
  __shared__ unsigned short xls[CROWS * CSTRIDE];   // 58384 B
  int b = blockIdx.x & 7, tb = blockIdx.x >> 3;     // grid 208 = 8 x 26
  int t0 = tb * CTN;
  int tid = threadIdx.x;
  {
    const int* idsb = ids + b * TSEQ;
    for (int idx = tid; idx < CROWS * 40; idx += 256) {
      int rr = idx / 40, c8 = idx % 40;
      int tau = t0 + rr;
      bool inr = (tau >= PADL) && (tau < PADL + TSEQ);
      unsigned short pk[8];
      if (inr) {
        int row = idsb[tau - PADL];
        const float* src = embed_w + (size_t)row * DDIM + c8 * 8;
        float4 lo = (c8 * 8 + 3 < DDIM) ? *(const float4*)&src[0] : make_float4(0, 0, 0, 0);
        float4 hi = (c8 * 8 + 7 < DDIM) ? *(const float4*)&src[4] : make_float4(0, 0, 0, 0);
        pk[0] = f2bf(lo.x); pk[1] = f2bf(lo.y); pk[2] = f2bf(lo.z); pk[3] = f2bf(lo.w);
        pk[4] = f2bf(hi.x); pk[5] = f2bf(hi.y); pk[6] = f2bf(hi.z); pk[7] = f2bf(hi.w);
      } else {
#pragma unroll
        for (int e = 0; e < 8; ++e) pk[e] = 0;
      }
      *(int4*)&xls[rr * CSTRIDE + c8 * 8] = *(const int4*)pk;
    }
  }
  __syncthreads();
  int w = tid >> 6, lane = tid & 63;
  int l15 = lane & 15, quad = lane >> 4;
  int ob = w * 80;                                  // o-quadrant per wave
  f4v acc[5][5];
#pragma unroll
  for (int mf = 0; mf < 5; ++mf) {
    float bv[4];
#pragma unroll
    for (int rr = 0; rr < 4; ++rr) {
      int o = ob + mf * 16 + quad * 4 + rr;
      bv[rr] = (o < DDIM) ? bias[o] : 0.0f;
    }
#pragma unroll
    for (int nf = 0; nf < 5; ++nf) {
      acc[mf][nf][0] = bv[0]; acc[mf][nf][1] = bv[1];
      acc[mf][nf][2] = bv[2]; acc[mf][nf][3] = bv[3];
    }
  }
  // A-frag (kc,it,mf) at wl[kc*DPAD*DPAD + mf*16*DPAD + it*32]
  const unsigned short* wl = wT + (size_t)(ob + l15) * DPAD + quad * 8;
  s8v Aping[5], Apong[5];
#pragma unroll
  for (int mf = 0; mf < 5; ++mf) Aping[mf] = *(const s8v*)&wl[mf * 16 * DPAD];        // (0,0)
#pragma unroll
  for (int mf = 0; mf < 5; ++mf) Apong[mf] = *(const s8v*)&wl[mf * 16 * DPAD + 32];   // (0,1)
  for (int ii = 0; ii < 100; ii += 2) {
    // ---- even sub-iter: frags (ii) in Aping
    {
      int kc = ii / 10, it = ii % 10;
      s8v Bv[5];
#pragma unroll
      for (int nf = 0; nf < 5; ++nf)
        Bv[nf] = *(const s8v*)&xls[(nf * 16 + l15 + kc) * CSTRIDE + it * 32 + quad * 8];
#pragma unroll
      for (int mf = 0; mf < 5; ++mf)
#pragma unroll
        for (int nf = 0; nf < 5; ++nf)
          acc[mf][nf] = __builtin_amdgcn_mfma_f32_16x16x32_bf16(Aping[mf], Bv[nf], acc[mf][nf], 0, 0, 0);
      int p = ii + 2;
      if (p < 100) {
        int kp = p / 10, itp = p % 10;
        const unsigned short* wp = wl + (size_t)kp * (DPAD * DPAD) + itp * 32;
#pragma unroll
        for (int mf = 0; mf < 5; ++mf) Aping[mf] = *(const s8v*)&wp[mf * 16 * DPAD];
      }
    }
    // ---- odd sub-iter: frags (ii+1) in Apong
    {
      int kc = (ii + 1) / 10, it = (ii + 1) % 10;
      s8v Bv[5];
#pragma unroll
      for (int nf = 0; nf < 5; ++nf)
        Bv[nf] = *(const s8v*)&xls[(nf * 16 + l15 + kc) * CSTRIDE + it * 32 + quad * 8];
#pragma unroll
      for (int mf = 0; mf < 5; ++mf)
#pragma unroll
        for (int nf = 0; nf < 5; ++nf)
          acc[mf][nf] = __builtin_amdgcn_mfma_f32_16x16x32_bf16(Apong[mf], Bv[nf], acc[mf][nf], 0, 0, 0);
      int p = ii + 3;
      if (p < 100) {
        int kp = p / 10, itp = p % 10;
        const unsigned short* wp = wl + (size_t)kp * (DPAD * DPAD) + itp * 32;
#pragma unroll
        for (int mf = 0; mf < 5; ++mf) Apong[mf] = *(const s8v*)&wp[mf * 16 * DPAD];
      }
    }
  }
#pragma unroll
  for (int mf = 0; mf < 5; ++mf) {
    int obase = ob + mf * 16 + quad * 4;
#pragma unroll
    for (int nf = 0; nf < 5; ++nf) {
      int t = t0 + nf * 16 + l15;            // always < TALLOC (26x80 = 2080 exact)
      bool live = t < TPRIME;
      unsigned short pk[4];
#pragma unroll
      for (int rr = 0; rr < 4; ++rr)
        pk[rr] = live ? f2bf(fmaxf(acc[mf][nf][rr], 0.0f)) : (unsigned short)0;
      *(uint2*)&h[((size_t)b * TALLOC + t) * DPAD + obase] = *(uint2*)pk;
    }
  }
}

// ---- K3: scores (U . h) via MFMA + fused softmax-weighted mean.
// FROZEN r5/r6/r11 local optimum (119us; best of 7 structural attempts — r6
// tweaks null, r7 T15 spilled, r8 8-wave +13, r9 no-LDS +330, r10 dist-2
// +32, r16 f32-U-direct +9 via doubled HBM traffic). 4 waves, depth-1 DMA
// double-buffer, vmcnt(0)+barrier per tile, all 560 blocks co-resident at
// (256,3). A[2][10] in AGPRs. Unmasked softmax (tail h rows exact zeros ->
// e=1) + (-23) phantom-column correction; setprio on MFMA.
__global__ __launch_bounds__(256, 3) void attn_mfma_kernel(
    const unsigned short* __restrict__ h, const unsigned short* __restrict__ Ub,
    const float* __restrict__ fcb, float* __restrict__ out) {
  __shared__ unsigned short hls[2 * TSTG * DPAD];   // 2 x 10240 elems = 40960B
  int b = blockIdx.x & 7, lb = blockIdx.x >> 3;
  int tid = threadIdx.x;
  int w = tid >> 6, lane = tid & 63;
  int l15 = lane & 15, quad = lane >> 4;
  const unsigned short* hb = h + (size_t)b * TALLOC * DPAD;

  // A fragments (U): wave covers 32 l-rows
  s8v A[2][10];
  {
    int lr0 = lb * 128 + w * 32 + l15;
#pragma unroll
    for (int mf = 0; mf < 2; ++mf) {
      int lr = lr0 + mf * 16;
      if (lr >= LPAD) lr = LPAD - 1;          // clamped rows masked at store
      const unsigned short* up = Ub + (size_t)lr * DPAD + quad * 8;
#pragma unroll
      for (int kc = 0; kc < 10; ++kc)
        A[mf][kc] = *(const s8v*)&up[kc * 32];
    }
  }

  // DMA staging map: wave w fills LDS elems [w*2560, w*2560+2560) in 5 x 1KB.
  // lane's LDS chunk g = w*320 + j*64 + lane -> row r = g/40, chunk c = g%40;
  // global source chunk = c ^ (r&7)  (involution, same XOR on read side)
  int srcoff[5];
#pragma unroll
  for (int j = 0; j < 5; ++j) {
    int g = w * 320 + j * 64 + lane;
    int r = g / 40, c = g % 40;
    srcoff[j] = r * DPAD + ((c ^ (r & 7)) * 8);
  }

  // prologue: DMA tile 0 -> buf0
#pragma unroll
  for (int j = 0; j < 5; ++j)
    __builtin_amdgcn_global_load_lds((gas_ptr)(const void*)(hb + srcoff[j]),
                                     (las_ptr)(void*)&hls[w * 2560 + j * 512],
                                     16, 0, 0);
  asm volatile("s_waitcnt vmcnt(0)" ::: "memory");
  __builtin_amdgcn_s_barrier();

  float se[2][4], sw[2][4];
#pragma unroll
  for (int mf = 0; mf < 2; ++mf)
#pragma unroll
    for (int r = 0; r < 4; ++r) { se[mf][r] = 0.0f; sw[mf][r] = 0.0f; }

  int xr8 = (l15 & 7) * 8;            // read-side XOR (elem units)
  int rowb0 = l15 * DPAD;             // nf=0 row base
  int rowb1 = (16 + l15) * DPAD;      // nf=1 row base
  int bufsel = 0;
  const f4v vzero = {0.0f, 0.0f, 0.0f, 0.0f};
  for (int t = 0; t < NTT; ++t) {
    // issue DMA for tile t+1 into the other buffer (latency hidden by compute)
    if (t + 1 < NTT) {
      const unsigned short* src = hb + (size_t)(t + 1) * TSTG * DPAD;
      int dstb = (bufsel ^ 1) * 10240 + w * 2560;
#pragma unroll
      for (int j = 0; j < 5; ++j)
        __builtin_amdgcn_global_load_lds((gas_ptr)(const void*)(src + srcoff[j]),
                                         (las_ptr)(void*)&hls[dstb + j * 512],
                                         16, 0, 0);
    }
    const unsigned short* bufc = &hls[bufsel * 10240];
    f4v a00, a01, a10, a11;
    __builtin_amdgcn_s_setprio(1);
    {
      int ko = (quad * 8) ^ xr8;
      s8v Bv0 = *(const s8v*)&bufc[rowb0 + ko];
      s8v Bv1 = *(const s8v*)&bufc[rowb1 + ko];
      a00 = __builtin_amdgcn_mfma_f32_16x16x32_bf16(A[0][0], Bv0, vzero, 0, 0, 0);
      a01 = __builtin_amdgcn_mfma_f32_16x16x32_bf16(A[0][0], Bv1, vzero, 0, 0, 0);
      a10 = __builtin_amdgcn_mfma_f32_16x16x32_bf16(A[1][0], Bv0, vzero, 0, 0, 0);
      a11 = __builtin_amdgcn_mfma_f32_16x16x32_bf16(A[1][0], Bv1, vzero, 0, 0, 0);
    }
#pragma unroll
    for (int kc = 1; kc < 10; ++kc) {
      int ko = (kc * 32 + quad * 8) ^ xr8;
      s8v Bv0 = *(const s8v*)&bufc[rowb0 + ko];
      s8v Bv1 = *(const s8v*)&bufc[rowb1 + ko];
      a00 = __builtin_amdgcn_mfma_f32_16x16x32_bf16(A[0][kc], Bv0, a00, 0, 0, 0);
      a01 = __builtin_amdgcn_mfma_f32_16x16x32_bf16(A[0][kc], Bv1, a01, 0, 0, 0);
      a10 = __builtin_amdgcn_mfma_f32_16x16x32_bf16(A[1][kc], Bv0, a10, 0, 0, 0);
      a11 = __builtin_amdgcn_mfma_f32_16x16x32_bf16(A[1][kc], Bv1, a11, 0, 0, 0);
    }
    __builtin_amdgcn_s_setprio(0);
    // unmasked fused softmax accumulation (tail h rows are exact zeros ->
    // s=0 -> e=1; corrected after the reduction)
#pragma unroll
    for (int r = 0; r < 4; ++r) {
      float s0 = a00[r], s1 = a01[r];
      float e0 = __expf(s0), e1 = __expf(s1);
      se[0][r] += e0 + e1;
      sw[0][r] = fmaf(e0, s0, sw[0][r]);
      sw[0][r] = fmaf(e1, s1, sw[0][r]);
      float s2 = a10[r], s3 = a11[r];
      float e2 = __expf(s2), e3 = __expf(s3);
      se[1][r] += e2 + e3;
      sw[1][r] = fmaf(e2, s2, sw[1][r]);
      sw[1][r] = fmaf(e3, s3, sw[1][r]);
    }
    // drain this iter's DMA (issued a full tile of compute ago), sync, swap
    asm volatile("s_waitcnt vmcnt(0)" ::: "memory");
    __builtin_amdgcn_s_barrier();
    bufsel ^= 1;
  }

  // reduce over the 16 t-columns (l15 lanes); subtract the 23 phantom columns
  // (TALLOC - TPRIME, each contributing exactly exp(0)=1) from the denominator.
#pragma unroll
  for (int mf = 0; mf < 2; ++mf)
#pragma unroll
    for (int r = 0; r < 4; ++r) {
      float a = se[mf][r], c = sw[mf][r];
#pragma unroll
      for (int off = 1; off < 16; off <<= 1) {
        a += __shfl_xor(a, off, 64);
        c += __shfl_xor(c, off, 64);
      }
      if (l15 == 0) {
        int l = lb * 128 + w * 32 + mf * 16 + quad * 4 + r;
        if (l < LDIM) out[(size_t)b * LDIM + l] = c / (a - 23.0f) + fcb[l];
      }
    }
}

extern "C" void kernel_launch(void* const* d_in, const int* in_sizes, int n_in,
                              void* d_out, int out_size, void* d_ws, size_t ws_size,
                              hipStream_t stream) {
  const int*   ids     = (const int*)d_in[0];
  const float* embed_w = (const float*)d_in[1];
  const float* conv_w  = (const float*)d_in[2];
  const float* conv_b  = (const float*)d_in[3];
  const float* U       = (const float*)d_in[4];
  const float* fc_bias = (const float*)d_in[5];
  float* out = (float*)d_out;

  unsigned char* p = (unsigned char*)d_ws;
  unsigned short* hb = (unsigned short*)p;                 p += (size_t)BATCH * TALLOC * DPAD * 2;
  unsigned short* wT = (unsigned short*)p;                 p += (size_t)KSZ * DPAD * DPAD * 2;
  unsigned short* Ub = (unsigned short*)p;

  hipLaunchKernelGGL(prep_kernel, dim3(DPAD + LPAD), dim3(256), 0, stream,
                     conv_w, U, wT, Ub);
  hipLaunchKernelGGL(conv_mfma_kernel, dim3(BATCH * 26), dim3(256), 0, stream,
                     ids, embed_w, wT, conv_b, hb);
  hipLaunchKernelGGL(attn_mfma_kernel, dim3(BATCH * LBLK), dim3(256), 0, stream,
                     hb, Ub, fc_bias, out);
}

// Round 18
// 284.019 us; speedup vs baseline: 1.0222x; 1.0161x over previous
//
#include <hip/hip_runtime.h>

#define VOCAB   50000
#define LDIM    8921
#define DDIM    300
#define DPAD    320
#define KSZ     10
#define BATCH   8
#define TSEQ    2048
#define PADL    9
#define TPRIME  2057
#define TPADDED 2066
#define LPAD    8928

// ---- attn tiling
#define TSTG    32                 // t rows per LDS tile
#define NTT     65                 // ceil(TPRIME/TSTG)
#define TALLOC  (NTT * TSTG)       // 2080 h rows per batch (tail rows zeroed by conv)
#define LBLK    70                 // ceil(LDIM/128) l-blocks

typedef short s8v __attribute__((ext_vector_type(8)));   // 8 x bf16 bits
typedef float f4v __attribute__((ext_vector_type(4)));

typedef const __attribute__((address_space(1))) unsigned int* gas_ptr;
typedef __attribute__((address_space(3))) unsigned int* las_ptr;

__device__ inline unsigned short f2bf(float f) {
  union { float f; unsigned u; } v; v.f = f;
  unsigned r = v.u + 0x7FFF + ((v.u >> 16) & 1);
  return (unsigned short)(r >> 16);
}

// ---- K1: conv weight transform + U transform (fused prep).
// Decomposition (r11/r12/r16): this whole kernel is ~3us; not worth touching.
__global__ __launch_bounds__(256) void prep_kernel(
    const float* __restrict__ w, const float* __restrict__ U,
    unsigned short* __restrict__ wT, unsigned short* __restrict__ Ub) {
  int bid = blockIdx.x;
  if (bid < KSZ * DPAD) {
    int k = bid / DPAD, o = bid % DPAD;
    for (int i = threadIdx.x; i < DPAD; i += 256) {
      float v = (o < DDIM && i < DDIM) ? w[((size_t)o * DDIM + i) * KSZ + k] : 0.0f;
      wT[((size_t)k * DPAD + o) * DPAD + i] = f2bf(v);
    }
  } else {
    int l = bid - KSZ * DPAD;
    for (int d = threadIdx.x; d < DPAD; d += 256) {
      float v = (l < LDIM && d < DDIM) ? U[(size_t)l * DDIM + d] : 0.0f;
      Ub[(size_t)l * DPAD + d] = f2bf(v);
    }
  }
}

// ---- K2: conv via MFMA with fused embedding gather — FROZEN (session best).
// Staging reads embed_w[ids[.]] f32 directly, converts to bf16 in-register,
// ds_writes (kills xp round-trip + gather kernel, r10). Main loop: grid 208 =
// 8 x 26 balanced (<=1 block/CU, zero makespan quantization, r5), acc[5][5],
// dist-2 Aping/Apong wT prefetch, bare (256) launch bounds.
// DEFENDED: r12 8-wave o-split -> VGPR demotion (60 regs, 132us); r14 k-split
// across waves -> null; r15 B register ping/pong -> null. ~82us slice,
// per-iteration pace is per-wave-serial.
#define CTN 80
#define CROWS 89          // CTN + KSZ - 1
#define CSTRIDE 328       // 656B/row -> benign 2-way conflicts
__global__ __launch_bounds__(256) void conv_mfma_kernel(
    const int* __restrict__ ids, const float* __restrict__ embed_w,
    const unsigned short* __restrict__ wT,
    const float* __restrict__ bias, unsigned short* __restrict__ h) {
  __shared__ unsigned short xls[CROWS * CSTRIDE];   // 58384 B
  int b = blockIdx.x & 7, tb = blockIdx.x >> 3;     // grid 208 = 8 x 26
  int t0 = tb * CTN;
  int tid = threadIdx.x;
  {
    const int* idsb = ids + b * TSEQ;
    for (int idx = tid; idx < CROWS * 40; idx += 256) {
      int rr = idx / 40, c8 = idx % 40;
      int tau = t0 + rr;
      bool inr = (tau >= PADL) && (tau < PADL + TSEQ);
      unsigned short pk[8];
      if (inr) {
        int row = idsb[tau - PADL];
        const float* src = embed_w + (size_t)row * DDIM + c8 * 8;
        float4 lo = (c8 * 8 + 3 < DDIM) ? *(const float4*)&src[0] : make_float4(0, 0, 0, 0);
        float4 hi = (c8 * 8 + 7 < DDIM) ? *(const float4*)&src[4] : make_float4(0, 0, 0, 0);
        pk[0] = f2bf(lo.x); pk[1] = f2bf(lo.y); pk[2] = f2bf(lo.z); pk[3] = f2bf(lo.w);
        pk[4] = f2bf(hi.x); pk[5] = f2bf(hi.y); pk[6] = f2bf(hi.z); pk[7] = f2bf(hi.w);
      } else {
#pragma unroll
        for (int e = 0; e < 8; ++e) pk[e] = 0;
      }
      *(int4*)&xls[rr * CSTRIDE + c8 * 8] = *(const int4*)pk;
    }
  }
  __syncthreads();
  int w = tid >> 6, lane = tid & 63;
  int l15 = lane & 15, quad = lane >> 4;
  int ob = w * 80;                                  // o-quadrant per wave
  f4v acc[5][5];
#pragma unroll
  for (int mf = 0; mf < 5; ++mf) {
    float bv[4];
#pragma unroll
    for (int rr = 0; rr < 4; ++rr) {
      int o = ob + mf * 16 + quad * 4 + rr;
      bv[rr] = (o < DDIM) ? bias[o] : 0.0f;
    }
#pragma unroll
    for (int nf = 0; nf < 5; ++nf) {
      acc[mf][nf][0] = bv[0]; acc[mf][nf][1] = bv[1];
      acc[mf][nf][2] = bv[2]; acc[mf][nf][3] = bv[3];
    }
  }
  // A-frag (kc,it,mf) at wl[kc*DPAD*DPAD + mf*16*DPAD + it*32]
  const unsigned short* wl = wT + (size_t)(ob + l15) * DPAD + quad * 8;
  s8v Aping[5], Apong[5];
#pragma unroll
  for (int mf = 0; mf < 5; ++mf) Aping[mf] = *(const s8v*)&wl[mf * 16 * DPAD];        // (0,0)
#pragma unroll
  for (int mf = 0; mf < 5; ++mf) Apong[mf] = *(const s8v*)&wl[mf * 16 * DPAD + 32];   // (0,1)
  for (int ii = 0; ii < 100; ii += 2) {
    // ---- even sub-iter: frags (ii) in Aping
    {
      int kc = ii / 10, it = ii % 10;
      s8v Bv[5];
#pragma unroll
      for (int nf = 0; nf < 5; ++nf)
        Bv[nf] = *(const s8v*)&xls[(nf * 16 + l15 + kc) * CSTRIDE + it * 32 + quad * 8];
#pragma unroll
      for (int mf = 0; mf < 5; ++mf)
#pragma unroll
        for (int nf = 0; nf < 5; ++nf)
          acc[mf][nf] = __builtin_amdgcn_mfma_f32_16x16x32_bf16(Aping[mf], Bv[nf], acc[mf][nf], 0, 0, 0);
      int p = ii + 2;
      if (p < 100) {
        int kp = p / 10, itp = p % 10;
        const unsigned short* wp = wl + (size_t)kp * (DPAD * DPAD) + itp * 32;
#pragma unroll
        for (int mf = 0; mf < 5; ++mf) Aping[mf] = *(const s8v*)&wp[mf * 16 * DPAD];
      }
    }
    // ---- odd sub-iter: frags (ii+1) in Apong
    {
      int kc = (ii + 1) / 10, it = (ii + 1) % 10;
      s8v Bv[5];
#pragma unroll
      for (int nf = 0; nf < 5; ++nf)
        Bv[nf] = *(const s8v*)&xls[(nf * 16 + l15 + kc) * CSTRIDE + it * 32 + quad * 8];
#pragma unroll
      for (int mf = 0; mf < 5; ++mf)
#pragma unroll
        for (int nf = 0; nf < 5; ++nf)
          acc[mf][nf] = __builtin_amdgcn_mfma_f32_16x16x32_bf16(Apong[mf], Bv[nf], acc[mf][nf], 0, 0, 0);
      int p = ii + 3;
      if (p < 100) {
        int kp = p / 10, itp = p % 10;
        const unsigned short* wp = wl + (size_t)kp * (DPAD * DPAD) + itp * 32;
#pragma unroll
        for (int mf = 0; mf < 5; ++mf) Apong[mf] = *(const s8v*)&wp[mf * 16 * DPAD];
      }
    }
  }
#pragma unroll
  for (int mf = 0; mf < 5; ++mf) {
    int obase = ob + mf * 16 + quad * 4;
#pragma unroll
    for (int nf = 0; nf < 5; ++nf) {
      int t = t0 + nf * 16 + l15;            // always < TALLOC (26x80 = 2080 exact)
      bool live = t < TPRIME;
      unsigned short pk[4];
#pragma unroll
      for (int rr = 0; rr < 4; ++rr)
        pk[rr] = live ? f2bf(fmaxf(acc[mf][nf][rr], 0.0f)) : (unsigned short)0;
      *(uint2*)&h[((size_t)b * TALLOC + t) * DPAD + obase] = *(uint2*)pk;
    }
  }
}

// ---- K3: scores (U . h) via MFMA + fused softmax-weighted mean — FROZEN
// (session best, 119us). 4 waves split L (32 l-rows each); A[2][10] U-frags
// resident in AGPRs (unified file; arch VGPR_Count 84). h streamed via
// global_load_lds DMA, depth-1 double buffer, involution-swizzled source
// chunks (c ^= r&7) + same XOR on reads -> zero bank conflicts.
// vmcnt(0)+barrier per tile; all 560 blocks co-resident at (256,3).
// Unmasked softmax (tail h rows are exact zeros -> e=exp(0)=1) with -23
// phantom-column denominator correction; setprio(1) around MFMA cluster.
// DEFENDED: r6 schedule tweaks null; r7 T15 2x-acc -> spill (+13); r8
// 8-wave -> +13; r9 no-LDS direct-global -> +330; r10 dist-2 counted
// vmcnt + stagger -> +32; r16 f32-U direct -> +9 (doubled HBM fetch).
__global__ __launch_bounds__(256, 3) void attn_mfma_kernel(
    const unsigned short* __restrict__ h, const unsigned short* __restrict__ Ub,
    const float* __restrict__ fcb, float* __restrict__ out) {
  __shared__ unsigned short hls[2 * TSTG * DPAD];   // 2 x 10240 elems = 40960B
  int b = blockIdx.x & 7, lb = blockIdx.x >> 3;
  int tid = threadIdx.x;
  int w = tid >> 6, lane = tid & 63;
  int l15 = lane & 15, quad = lane >> 4;
  const unsigned short* hb = h + (size_t)b * TALLOC * DPAD;

  // A fragments (U): wave covers 32 l-rows
  s8v A[2][10];
  {
    int lr0 = lb * 128 + w * 32 + l15;
#pragma unroll
    for (int mf = 0; mf < 2; ++mf) {
      int lr = lr0 + mf * 16;
      if (lr >= LPAD) lr = LPAD - 1;          // clamped rows masked at store
      const unsigned short* up = Ub + (size_t)lr * DPAD + quad * 8;
#pragma unroll
      for (int kc = 0; kc < 10; ++kc)
        A[mf][kc] = *(const s8v*)&up[kc * 32];
    }
  }

  // DMA staging map: wave w fills LDS elems [w*2560, w*2560+2560) in 5 x 1KB.
  // lane's LDS chunk g = w*320 + j*64 + lane -> row r = g/40, chunk c = g%40;
  // global source chunk = c ^ (r&7)  (involution, same XOR on read side)
  int srcoff[5];
#pragma unroll
  for (int j = 0; j < 5; ++j) {
    int g = w * 320 + j * 64 + lane;
    int r = g / 40, c = g % 40;
    srcoff[j] = r * DPAD + ((c ^ (r & 7)) * 8);
  }

  // prologue: DMA tile 0 -> buf0
#pragma unroll
  for (int j = 0; j < 5; ++j)
    __builtin_amdgcn_global_load_lds((gas_ptr)(const void*)(hb + srcoff[j]),
                                     (las_ptr)(void*)&hls[w * 2560 + j * 512],
                                     16, 0, 0);
  asm volatile("s_waitcnt vmcnt(0)" ::: "memory");
  __builtin_amdgcn_s_barrier();

  float se[2][4], sw[2][4];
#pragma unroll
  for (int mf = 0; mf < 2; ++mf)
#pragma unroll
    for (int r = 0; r < 4; ++r) { se[mf][r] = 0.0f; sw[mf][r] = 0.0f; }

  int xr8 = (l15 & 7) * 8;            // read-side XOR (elem units)
  int rowb0 = l15 * DPAD;             // nf=0 row base
  int rowb1 = (16 + l15) * DPAD;      // nf=1 row base
  int bufsel = 0;
  const f4v vzero = {0.0f, 0.0f, 0.0f, 0.0f};
  for (int t = 0; t < NTT; ++t) {
    // issue DMA for tile t+1 into the other buffer (latency hidden by compute)
    if (t + 1 < NTT) {
      const unsigned short* src = hb + (size_t)(t + 1) * TSTG * DPAD;
      int dstb = (bufsel ^ 1) * 10240 + w * 2560;
#pragma unroll
      for (int j = 0; j < 5; ++j)
        __builtin_amdgcn_global_load_lds((gas_ptr)(const void*)(src + srcoff[j]),
                                         (las_ptr)(void*)&hls[dstb + j * 512],
                                         16, 0, 0);
    }
    const unsigned short* bufc = &hls[bufsel * 10240];
    f4v a00, a01, a10, a11;
    __builtin_amdgcn_s_setprio(1);
    {
      int ko = (quad * 8) ^ xr8;
      s8v Bv0 = *(const s8v*)&bufc[rowb0 + ko];
      s8v Bv1 = *(const s8v*)&bufc[rowb1 + ko];
      a00 = __builtin_amdgcn_mfma_f32_16x16x32_bf16(A[0][0], Bv0, vzero, 0, 0, 0);
      a01 = __builtin_amdgcn_mfma_f32_16x16x32_bf16(A[0][0], Bv1, vzero, 0, 0, 0);
      a10 = __builtin_amdgcn_mfma_f32_16x16x32_bf16(A[1][0], Bv0, vzero, 0, 0, 0);
      a11 = __builtin_amdgcn_mfma_f32_16x16x32_bf16(A[1][0], Bv1, vzero, 0, 0, 0);
    }
#pragma unroll
    for (int kc = 1; kc < 10; ++kc) {
      int ko = (kc * 32 + quad * 8) ^ xr8;
      s8v Bv0 = *(const s8v*)&bufc[rowb0 + ko];
      s8v Bv1 = *(const s8v*)&bufc[rowb1 + ko];
      a00 = __builtin_amdgcn_mfma_f32_16x16x32_bf16(A[0][kc], Bv0, a00, 0, 0, 0);
      a01 = __builtin_amdgcn_mfma_f32_16x16x32_bf16(A[0][kc], Bv1, a01, 0, 0, 0);
      a10 = __builtin_amdgcn_mfma_f32_16x16x32_bf16(A[1][kc], Bv0, a10, 0, 0, 0);
      a11 = __builtin_amdgcn_mfma_f32_16x16x32_bf16(A[1][kc], Bv1, a11, 0, 0, 0);
    }
    __builtin_amdgcn_s_setprio(0);
    // unmasked fused softmax accumulation (tail h rows are exact zeros ->
    // s=0 -> e=1; corrected after the reduction)
#pragma unroll
    for (int r = 0; r < 4; ++r) {
      float s0 = a00[r], s1 = a01[r];
      float e0 = __expf(s0), e1 = __expf(s1);
      se[0][r] += e0 + e1;
      sw[0][r] = fmaf(e0, s0, sw[0][r]);
      sw[0][r] = fmaf(e1, s1, sw[0][r]);
      float s2 = a10[r], s3 = a11[r];
      float e2 = __expf(s2), e3 = __expf(s3);
      se[1][r] += e2 + e3;
      sw[1][r] = fmaf(e2, s2, sw[1][r]);
      sw[1][r] = fmaf(e3, s3, sw[1][r]);
    }
    // drain this iter's DMA (issued a full tile of compute ago), sync, swap
    asm volatile("s_waitcnt vmcnt(0)" ::: "memory");
    __builtin_amdgcn_s_barrier();
    bufsel ^= 1;
  }

  // reduce over the 16 t-columns (l15 lanes); subtract the 23 phantom columns
  // (TALLOC - TPRIME, each contributing exactly exp(0)=1) from the denominator.
#pragma unroll
  for (int mf = 0; mf < 2; ++mf)
#pragma unroll
    for (int r = 0; r < 4; ++r) {
      float a = se[mf][r], c = sw[mf][r];
#pragma unroll
      for (int off = 1; off < 16; off <<= 1) {
        a += __shfl_xor(a, off, 64);
        c += __shfl_xor(c, off, 64);
      }
      if (l15 == 0) {
        int l = lb * 128 + w * 32 + mf * 16 + quad * 4 + r;
        if (l < LDIM) out[(size_t)b * LDIM + l] = c / (a - 23.0f) + fcb[l];
      }
    }
}

extern "C" void kernel_launch(void* const* d_in, const int* in_sizes, int n_in,
                              void* d_out, int out_size, void* d_ws, size_t ws_size,
                              hipStream_t stream) {
  const int*   ids     = (const int*)d_in[0];
  const float* embed_w = (const float*)d_in[1];
  const float* conv_w  = (const float*)d_in[2];
  const float* conv_b  = (const float*)d_in[3];
  const float* U       = (const float*)d_in[4];
  const float* fc_bias = (const float*)d_in[5];
  float* out = (float*)d_out;

  unsigned char* p = (unsigned char*)d_ws;
  unsigned short* hb = (unsigned short*)p;                 p += (size_t)BATCH * TALLOC * DPAD * 2;
  unsigned short* wT = (unsigned short*)p;                 p += (size_t)KSZ * DPAD * DPAD * 2;
  unsigned short* Ub = (unsigned short*)p;

  hipLaunchKernelGGL(prep_kernel, dim3(KSZ * DPAD + LPAD), dim3(256), 0, stream,
                     conv_w, U, wT, Ub);
  hipLaunchKernelGGL(conv_mfma_kernel, dim3(BATCH * 26), dim3(256), 0, stream,
                     ids, embed_w, wT, conv_b, hb);
  hipLaunchKernelGGL(attn_mfma_kernel, dim3(BATCH * LBLK), dim3(256), 0, stream,
                     hb, Ub, fc_bias, out);
}